// Round 6
// baseline (138.503 us; speedup 1.0000x reference)
//
#include <hip/hip_runtime.h>
#include <hip/hip_bf16.h>
#include <stdint.h>

#define NS_ 4096
#define M_  8192
#define D_  256
#define TEMP 0.07f
#define EXP_SCALE 20.61707212818536f   // log2(e)/0.07 : exp(sim/T) = exp2(sim*EXP_SCALE)
#define LN2 0.6931471805599453f
#define CQ_ 16                          // col-blocks per rtile (16 x 512 cols)

typedef short bf16x8 __attribute__((ext_vector_type(8)));
typedef float f32x4  __attribute__((ext_vector_type(4)));
typedef unsigned short ushortx4 __attribute__((ext_vector_type(4)));

static __device__ inline unsigned short f2bf(float x) {
    unsigned u = __float_as_uint(x);
    u += 0x7fffu + ((u >> 16) & 1u);
    return (unsigned short)(u >> 16);
}

static __device__ inline float cleanf(float v) {
    return __builtin_isfinite(v) ? v : 0.0f;
}

// async 16B global -> LDS (lane-contiguous LDS destination required)
#define LDS_LOAD16(gp, lp) \
    __builtin_amdgcn_global_load_lds((const __attribute__((address_space(1))) uint32_t*)(gp), \
                                     (__attribute__((address_space(3))) uint32_t*)(lp), 16, 0, 0)

// ---------------- Kernel 1: clean + normalize -> bf16 F, fp32 pos[]; zero denom/cnt/out -
// grid = NS_, block = 64 (one wave per paired row)
__global__ __launch_bounds__(64) void knorm(const float* __restrict__ z1,
                                            const float* __restrict__ z2,
                                            short* __restrict__ F,
                                            float* __restrict__ pos,
                                            float* __restrict__ denom,
                                            int* __restrict__ cnt,
                                            float* __restrict__ out) {
    const int i = blockIdx.x;
    const int t = threadIdx.x;
    const float4* p1 = (const float4*)(z1 + (size_t)i * D_);
    const float4* p2 = (const float4*)(z2 + (size_t)i * D_);
    float4 a = p1[t], b = p2[t];
    a.x = cleanf(a.x); a.y = cleanf(a.y); a.z = cleanf(a.z); a.w = cleanf(a.w);
    b.x = cleanf(b.x); b.y = cleanf(b.y); b.z = cleanf(b.z); b.w = cleanf(b.w);

    float s1 = a.x*a.x + a.y*a.y + a.z*a.z + a.w*a.w;
    float s2 = b.x*b.x + b.y*b.y + b.z*b.z + b.w*b.w;
    float dp = a.x*b.x + a.y*b.y + a.z*b.z + a.w*b.w;
    #pragma unroll
    for (int m = 1; m < 64; m <<= 1) {
        s1 += __shfl_xor(s1, m);
        s2 += __shfl_xor(s2, m);
        dp += __shfl_xor(dp, m);
    }
    const float inv1 = 1.0f / fmaxf(sqrtf(s1), 1e-12f);
    const float inv2 = 1.0f / fmaxf(sqrtf(s2), 1e-12f);

    ushortx4 o1, o2;
    o1.x = f2bf(a.x * inv1); o1.y = f2bf(a.y * inv1); o1.z = f2bf(a.z * inv1); o1.w = f2bf(a.w * inv1);
    o2.x = f2bf(b.x * inv2); o2.y = f2bf(b.y * inv2); o2.z = f2bf(b.z * inv2); o2.w = f2bf(b.w * inv2);
    ((ushortx4*)(F + (size_t)i * D_))[t]          = o1;
    ((ushortx4*)(F + (size_t)(i + NS_) * D_))[t]  = o2;

    if (t == 0) pos[i] = dp * inv1 * inv2;       // exact fp32 positive sim
    if (t < 2)  denom[i * 2 + t] = 0.0f;         // zero denom (2 per block x 4096)
    if (i == 0) cnt[t] = 0;                      // zero 64 rtile counters
    if (i == 0 && t == 0) out[0] = 0.0f;         // zero loss accumulator
}

// ---------------- Kernel 2: fused sim-GEMM + row exp-sums + finishers -------------------
// grid = 1024 = 64 rtiles (128 rows) x 16 col-blocks (512 cols) -> exactly 4 blocks/CU.
// 256 thr / 4 waves; wave w owns rows R0 + w*32 + [0,32) as 2 strips of 16 (A = 64 VGPR,
// K=256 resident). B: 8 groups of 64 cols staged via global_load_lds + XOR swizzle;
// each bfrag feeds 2 MFMAs. Low VGPR (<=128) => 4 waves/SIMD for latency hiding.
__global__ __launch_bounds__(256, 4) void kgemm(const short* __restrict__ F,
                                                float* __restrict__ denom,
                                                int* __restrict__ cnt,
                                                const float* __restrict__ pos,
                                                float* __restrict__ out) {
    __shared__ short Bl[64 * 256];   // 32 KB staging tile, 16B chunks XOR-swizzled
    __shared__ int lastflag;
    __shared__ float red[4];

    const int rtile = blockIdx.x >> 4;   // 64 rtiles
    const int cq    = blockIdx.x & 15;   // 16 col-blocks
    const int R0 = rtile * 128;
    const int C0 = cq * 512;

    const int tid  = threadIdx.x;
    const int lane = tid & 63;
    const int wave = tid >> 6;
    const int c16  = lane & 15;
    const int quad = lane >> 4;
    const int swz  = c16 & 7;

    // ---- A prologue: 2 chunks of 64 rows staged coalesced; waves extract their strips
    bf16x8 afrag[2][8];
    #pragma unroll
    for (int ch = 0; ch < 2; ++ch) {
        __syncthreads();
        const short* ga = F + (size_t)(R0 + ch * 64) * D_;
        #pragma unroll
        for (int r2 = 0; r2 < 8; ++r2) {
            int c   = tid + r2 * 256;
            int row = c >> 5;
            int kg  = (c & 31) ^ (row & 7);
            LDS_LOAD16(ga + row * D_ + kg * 8, Bl + c * 8);
        }
        __syncthreads();
        if ((wave >> 1) == ch) {
            #pragma unroll
            for (int s = 0; s < 2; ++s) {
                const int lr = (wave & 1) * 32 + s * 16 + c16;
                #pragma unroll
                for (int ks = 0; ks < 8; ++ks)
                    afrag[s][ks] = *(const bf16x8*)(Bl + lr * 256 +
                                                    (((ks * 4 + quad) ^ (lr & 7)) * 8));
            }
        }
    }

    float accexp[2][4];
    #pragma unroll
    for (int s = 0; s < 2; ++s)
        #pragma unroll
        for (int r = 0; r < 4; ++r) accexp[s][r] = 0.0f;

    // ---- main loop: 8 B-groups of 64 cols
    for (int it = 0; it < 8; ++it) {
        __syncthreads();                       // previous tile's reads done
        const short* gb = F + (size_t)(C0 + it * 64) * D_;
        #pragma unroll
        for (int r2 = 0; r2 < 8; ++r2) {
            int c   = tid + r2 * 256;
            int row = c >> 5;
            int kg  = (c & 31) ^ (row & 7);
            LDS_LOAD16(gb + row * D_ + kg * 8, Bl + c * 8);
        }
        __syncthreads();                       // staging complete

        #pragma unroll
        for (int sub = 0; sub < 4; ++sub) {
            const int tc = sub * 16 + c16;     // tile col owned by this lane
            const short* bbase = Bl + tc * 256;
            f32x4 acc0 = (f32x4){0.f, 0.f, 0.f, 0.f};
            f32x4 acc1 = (f32x4){0.f, 0.f, 0.f, 0.f};
            // two batches of 4 bfrags to cap live registers
            #pragma unroll
            for (int h = 0; h < 2; ++h) {
                bf16x8 bfrag[4];
                #pragma unroll
                for (int k2 = 0; k2 < 4; ++k2)
                    bfrag[k2] = *(const bf16x8*)(bbase +
                                 ((((h * 4 + k2) * 4 + quad) ^ swz) * 8));
                #pragma unroll
                for (int k2 = 0; k2 < 4; ++k2) {
                    acc0 = __builtin_amdgcn_mfma_f32_16x16x32_bf16(
                        afrag[0][h * 4 + k2], bfrag[k2], acc0, 0, 0, 0);
                    acc1 = __builtin_amdgcn_mfma_f32_16x16x32_bf16(
                        afrag[1][h * 4 + k2], bfrag[k2], acc1, 0, 0, 0);
                }
            }

            const int colbase = C0 + it * 64 + sub * 16;
            #pragma unroll
            for (int s = 0; s < 2; ++s) {
                const f32x4 acc = s ? acc1 : acc0;
                const int rowbase = R0 + wave * 32 + s * 16;
                if (colbase != rowbase) {            // uniform fast path
                    #pragma unroll
                    for (int r = 0; r < 4; ++r)
                        accexp[s][r] += __builtin_amdgcn_exp2f(acc[r] * EXP_SCALE);
                } else {                             // diagonal 16x16 tile
                    #pragma unroll
                    for (int r = 0; r < 4; ++r) {
                        float e = __builtin_amdgcn_exp2f(acc[r] * EXP_SCALE);
                        if (c16 == quad * 4 + r) e = 0.0f;
                        accexp[s][r] += e;
                    }
                }
            }
        }
    }

    // row sums across the 16 lanes holding each row, one atomic per row
    #pragma unroll
    for (int s = 0; s < 2; ++s)
        #pragma unroll
        for (int r = 0; r < 4; ++r) {
            float v = accexp[s][r];
            v += __shfl_xor(v, 1);
            v += __shfl_xor(v, 2);
            v += __shfl_xor(v, 4);
            v += __shfl_xor(v, 8);
            if (c16 == 0)
                atomicAdd(&denom[R0 + wave * 32 + s * 16 + quad * 4 + r], v);
        }

    // last of 16 blocks per rtile: sum(log(denom[R0..R0+128))) / M -> out (+ pos term)
    __syncthreads();
    if (tid == 0) {
        __threadfence();                              // release our denom adds
        lastflag = (atomicAdd(&cnt[rtile], 1) == CQ_ - 1);
    }
    __syncthreads();
    if (lastflag) {
        float p = 0.0f;
        if (tid < 128) {
            __threadfence();                          // acquire others' denom adds
            float v = atomicAdd(&denom[R0 + tid], 0.0f);  // coherent read
            p = __builtin_amdgcn_logf(v) * (LN2 / (float)M_);
        }
        #pragma unroll
        for (int m = 1; m < 64; m <<= 1) p += __shfl_xor(p, m);
        if (lane == 0) red[wave] = p;
        __syncthreads();
        if (tid == 0) atomicAdd(out, red[0] + red[1] + red[2] + red[3]);
        if (rtile == 0) {                             // pos ready (knorm precedes)
            __syncthreads();                          // protect red reuse
            float sp = 0.0f;
            for (int i = tid; i < NS_; i += 256) sp += pos[i];
            #pragma unroll
            for (int m = 1; m < 64; m <<= 1) sp += __shfl_xor(sp, m);
            if (lane == 0) red[wave] = sp;
            __syncthreads();
            if (tid == 0)
                atomicAdd(out, (red[0] + red[1] + red[2] + red[3]) *
                               (-2.0f / (TEMP * (float)M_)));
        }
    }
}

extern "C" void kernel_launch(void* const* d_in, const int* in_sizes, int n_in,
                              void* d_out, int out_size, void* d_ws, size_t ws_size,
                              hipStream_t stream) {
    const float* z1 = (const float*)d_in[0];
    const float* z2 = (const float*)d_in[1];

    short* F     = (short*)d_ws;                                   // 4 MB
    float* denom = (float*)((char*)d_ws + (size_t)M_ * D_ * 2);    // 32 KB
    int*   cnt   = (int*)(denom + M_);                             // 256 B
    float* pos   = (float*)(cnt + 64);                             // 16 KB
    float* out   = (float*)d_out;

    knorm<<<NS_, 64, 0, stream>>>(z1, z2, F, pos, denom, cnt, out);
    kgemm<<<64 * CQ_, 256, 0, stream>>>(F, denom, cnt, pos, out);
}

// Round 7
// 133.577 us; speedup vs baseline: 1.0369x; 1.0369x over previous
//
#include <hip/hip_runtime.h>
#include <hip/hip_bf16.h>
#include <stdint.h>

#define NS_ 4096
#define M_  8192
#define D_  256
#define TEMP 0.07f
#define EXP_SCALE 20.61707212818536f   // log2(e)/0.07 : exp(sim/T) = exp2(sim*EXP_SCALE)
#define LN2 0.6931471805599453f
#define CQ_ 8                           // col-blocks per rtile (8 x 1024 cols)
#define ITERS 16                        // 1024 cols / 64-col tiles

typedef short bf16x8 __attribute__((ext_vector_type(8)));
typedef float f32x4  __attribute__((ext_vector_type(4)));
typedef unsigned short ushortx4 __attribute__((ext_vector_type(4)));

static __device__ inline unsigned short f2bf(float x) {
    unsigned u = __float_as_uint(x);
    u += 0x7fffu + ((u >> 16) & 1u);
    return (unsigned short)(u >> 16);
}

static __device__ inline float cleanf(float v) {
    return __builtin_isfinite(v) ? v : 0.0f;
}

// async 16B global -> LDS (lane-contiguous LDS destination required)
#define LDS_LOAD16(gp, lp) \
    __builtin_amdgcn_global_load_lds((const __attribute__((address_space(1))) uint32_t*)(gp), \
                                     (__attribute__((address_space(3))) uint32_t*)(lp), 16, 0, 0)

static __device__ inline void wait_ge(int* p, int target) {
    while (__hip_atomic_load(p, __ATOMIC_ACQUIRE, __HIP_MEMORY_SCOPE_WORKGROUP) < target)
        __builtin_amdgcn_s_sleep(1);
}

// ---------------- Kernel 1: clean + normalize -> bf16 F, fp32 pos[]; zero denom/cnt/out -
// grid = 1024, block = 256 (4 waves, one wave per paired row)
__global__ __launch_bounds__(256) void knorm(const float* __restrict__ z1,
                                             const float* __restrict__ z2,
                                             short* __restrict__ F,
                                             float* __restrict__ pos,
                                             float* __restrict__ denom,
                                             int* __restrict__ cnt,
                                             float* __restrict__ out) {
    const int wave = threadIdx.x >> 6;
    const int t    = threadIdx.x & 63;
    const int i    = blockIdx.x * 4 + wave;       // 0..NS-1
    const float4* p1 = (const float4*)(z1 + (size_t)i * D_);
    const float4* p2 = (const float4*)(z2 + (size_t)i * D_);
    float4 a = p1[t], b = p2[t];
    a.x = cleanf(a.x); a.y = cleanf(a.y); a.z = cleanf(a.z); a.w = cleanf(a.w);
    b.x = cleanf(b.x); b.y = cleanf(b.y); b.z = cleanf(b.z); b.w = cleanf(b.w);

    float s1 = a.x*a.x + a.y*a.y + a.z*a.z + a.w*a.w;
    float s2 = b.x*b.x + b.y*b.y + b.z*b.z + b.w*b.w;
    float dp = a.x*b.x + a.y*b.y + a.z*b.z + a.w*b.w;
    #pragma unroll
    for (int m = 1; m < 64; m <<= 1) {
        s1 += __shfl_xor(s1, m);
        s2 += __shfl_xor(s2, m);
        dp += __shfl_xor(dp, m);
    }
    const float inv1 = 1.0f / fmaxf(sqrtf(s1), 1e-12f);
    const float inv2 = 1.0f / fmaxf(sqrtf(s2), 1e-12f);

    ushortx4 o1, o2;
    o1.x = f2bf(a.x * inv1); o1.y = f2bf(a.y * inv1); o1.z = f2bf(a.z * inv1); o1.w = f2bf(a.w * inv1);
    o2.x = f2bf(b.x * inv2); o2.y = f2bf(b.y * inv2); o2.z = f2bf(b.z * inv2); o2.w = f2bf(b.w * inv2);
    ((ushortx4*)(F + (size_t)i * D_))[t]          = o1;
    ((ushortx4*)(F + (size_t)(i + NS_) * D_))[t]  = o2;

    if (t == 0) pos[i] = dp * inv1 * inv2;                 // exact fp32 positive sim
    const int gid = blockIdx.x * 256 + threadIdx.x;
    if (gid < M_)  denom[gid] = 0.0f;
    if (gid < 64)  cnt[gid] = 0;
    if (gid == 0)  out[0] = 0.0f;
}

// ---------------- Kernel 2: producer/consumer fused sim-GEMM ----------------------------
// grid = 512 = 64 rtiles (128 rows) x 8 col-blocks (1024 cols); 320 thr = 4 consumer
// waves (32 rows each, afrag K=256 resident) + 1 producer wave. B tiles (64 cols, 32 KB)
// flow through a 2-buffer LDS ring with LDS epoch flags; consumers never hit a barrier
// or vmcnt(0) drain in the main loop — the producer's drain overlaps consumer MFMA.
__global__ __launch_bounds__(320, 2) void kgemm(const short* __restrict__ F,
                                                float* __restrict__ denom,
                                                int* __restrict__ cnt,
                                                const float* __restrict__ pos,
                                                float* __restrict__ out) {
    __shared__ short Bl[2][64 * 256];   // 2 x 32 KB ring, 16B chunks XOR-swizzled
    __shared__ int ready[2], done[2];
    __shared__ int lastflag;
    __shared__ float red[5];

    const int rtile = blockIdx.x >> 3;   // 64 rtiles
    const int cq    = blockIdx.x & 7;    // 8 col-blocks
    const int R0 = rtile * 128;
    const int C0 = cq * 1024;

    const int tid  = threadIdx.x;
    const int lane = tid & 63;
    const int wave = tid >> 6;           // 0..3 consumers, 4 producer
    const int c16  = lane & 15;
    const int quad = lane >> 4;
    const int swz  = c16 & 7;

    // ---- A prologue: 2 chunks of 64 rows staged by consumer threads; strips extracted
    bf16x8 afrag[2][8];
    #pragma unroll
    for (int ch = 0; ch < 2; ++ch) {
        __syncthreads();
        if (tid < 256) {
            const short* ga = F + (size_t)(R0 + ch * 64) * D_;
            #pragma unroll
            for (int r2 = 0; r2 < 8; ++r2) {
                int c   = tid + r2 * 256;
                int row = c >> 5;
                int kg  = (c & 31) ^ (row & 7);
                LDS_LOAD16(ga + row * D_ + kg * 8, &Bl[0][0] + c * 8);
            }
        }
        __syncthreads();
        if (wave < 4 && (wave >> 1) == ch) {
            #pragma unroll
            for (int s = 0; s < 2; ++s) {
                const int lr = (wave & 1) * 32 + s * 16 + c16;
                #pragma unroll
                for (int ks = 0; ks < 8; ++ks)
                    afrag[s][ks] = *(const bf16x8*)(&Bl[0][0] + lr * 256 +
                                                    (((ks * 4 + quad) ^ swz) * 8));
            }
        }
    }
    if (tid == 0) { ready[0] = 0; ready[1] = 0; done[0] = 0; done[1] = 0; }
    __syncthreads();   // afrag ds_reads drained (lgkmcnt) before producer may overwrite

    float accexp[2][4];
    #pragma unroll
    for (int s = 0; s < 2; ++s)
        #pragma unroll
        for (int r = 0; r < 4; ++r) accexp[s][r] = 0.0f;

    if (wave == 4) {
        // -------- producer: fill ring buffers, drain vmcnt privately, publish epoch ----
        for (int it = 0; it < ITERS; ++it) {
            const int b = it & 1, f = it >> 1;
            if (it >= 2) wait_ge(&done[b], 4 * f);          // 4 consumers per fill
            const short* gb = F + (size_t)(C0 + it * 64) * D_;
            #pragma unroll
            for (int j = 0; j < 32; ++j) {
                int c   = (j << 6) | lane;
                int row = c >> 5;
                int kg  = (c & 31) ^ (row & 7);
                LDS_LOAD16(gb + row * D_ + kg * 8, &Bl[b][0] + c * 8);
            }
            asm volatile("s_waitcnt vmcnt(0)" ::: "memory");
            if (lane == 0)
                __hip_atomic_store(&ready[b], f + 1, __ATOMIC_RELEASE,
                                   __HIP_MEMORY_SCOPE_WORKGROUP);
        }
    } else {
        // -------- consumers: 32 rows each, no barriers, no vmcnt stalls ----------------
        for (int it = 0; it < ITERS; ++it) {
            const int b = it & 1, f = it >> 1;
            wait_ge(&ready[b], f + 1);
            const short* bb = &Bl[b][0];
            #pragma unroll
            for (int sub = 0; sub < 4; ++sub) {
                const int tc = sub * 16 + c16;
                const short* bbase = bb + tc * 256;
                f32x4 acc0 = (f32x4){0.f, 0.f, 0.f, 0.f};
                f32x4 acc1 = (f32x4){0.f, 0.f, 0.f, 0.f};
                #pragma unroll
                for (int h = 0; h < 2; ++h) {
                    bf16x8 bfrag[4];
                    #pragma unroll
                    for (int k2 = 0; k2 < 4; ++k2)
                        bfrag[k2] = *(const bf16x8*)(bbase +
                                     ((((h * 4 + k2) * 4 + quad) ^ swz) * 8));
                    #pragma unroll
                    for (int k2 = 0; k2 < 4; ++k2) {
                        acc0 = __builtin_amdgcn_mfma_f32_16x16x32_bf16(
                            afrag[0][h * 4 + k2], bfrag[k2], acc0, 0, 0, 0);
                        acc1 = __builtin_amdgcn_mfma_f32_16x16x32_bf16(
                            afrag[1][h * 4 + k2], bfrag[k2], acc1, 0, 0, 0);
                    }
                }
                const int colbase = C0 + it * 64 + sub * 16;
                #pragma unroll
                for (int s = 0; s < 2; ++s) {
                    const f32x4 acc = s ? acc1 : acc0;
                    const int rowbase = R0 + wave * 32 + s * 16;
                    if (colbase != rowbase) {
                        #pragma unroll
                        for (int r = 0; r < 4; ++r)
                            accexp[s][r] += __builtin_amdgcn_exp2f(acc[r] * EXP_SCALE);
                    } else {
                        #pragma unroll
                        for (int r = 0; r < 4; ++r) {
                            float e = __builtin_amdgcn_exp2f(acc[r] * EXP_SCALE);
                            if (c16 == quad * 4 + r) e = 0.0f;
                            accexp[s][r] += e;
                        }
                    }
                }
            }
            if (lane == 0)
                __hip_atomic_fetch_add(&done[b], 1, __ATOMIC_RELEASE,
                                       __HIP_MEMORY_SCOPE_WORKGROUP);
        }
        // row sums across the 16 lanes holding each row, one atomic per row
        #pragma unroll
        for (int s = 0; s < 2; ++s)
            #pragma unroll
            for (int r = 0; r < 4; ++r) {
                float v = accexp[s][r];
                v += __shfl_xor(v, 1);
                v += __shfl_xor(v, 2);
                v += __shfl_xor(v, 4);
                v += __shfl_xor(v, 8);
                if (c16 == 0)
                    atomicAdd(&denom[R0 + wave * 32 + s * 16 + quad * 4 + r], v);
            }
    }

    // last of 8 blocks per rtile: sum(log(denom[R0..R0+128))) / M -> out (+ pos term)
    __syncthreads();
    if (tid == 0) {
        __threadfence();                              // release our denom adds
        lastflag = (atomicAdd(&cnt[rtile], 1) == CQ_ - 1);
    }
    __syncthreads();
    if (lastflag) {
        float p = 0.0f;
        if (tid < 128) {
            __threadfence();                          // acquire others' denom adds
            float v = atomicAdd(&denom[R0 + tid], 0.0f);  // coherent read
            p = __builtin_amdgcn_logf(v) * (LN2 / (float)M_);
        }
        #pragma unroll
        for (int m = 1; m < 64; m <<= 1) p += __shfl_xor(p, m);
        if (lane == 0) red[wave] = p;
        __syncthreads();
        if (tid == 0) atomicAdd(out, red[0] + red[1] + red[2] + red[3] + red[4]);
        if (rtile == 0) {                             // pos ready (knorm precedes)
            __syncthreads();                          // protect red reuse
            float sp = 0.0f;
            for (int i = tid; i < NS_; i += 320) sp += pos[i];
            #pragma unroll
            for (int m = 1; m < 64; m <<= 1) sp += __shfl_xor(sp, m);
            if (lane == 0) red[wave] = sp;
            __syncthreads();
            if (tid == 0)
                atomicAdd(out, (red[0] + red[1] + red[2] + red[3] + red[4]) *
                               (-2.0f / (TEMP * (float)M_)));
        }
    }
}

extern "C" void kernel_launch(void* const* d_in, const int* in_sizes, int n_in,
                              void* d_out, int out_size, void* d_ws, size_t ws_size,
                              hipStream_t stream) {
    const float* z1 = (const float*)d_in[0];
    const float* z2 = (const float*)d_in[1];

    short* F     = (short*)d_ws;                                   // 4 MB
    float* denom = (float*)((char*)d_ws + (size_t)M_ * D_ * 2);    // 32 KB
    int*   cnt   = (int*)(denom + M_);                             // 256 B
    float* pos   = (float*)(cnt + 64);                             // 16 KB
    float* out   = (float*)d_out;

    knorm<<<NS_ / 4, 256, 0, stream>>>(z1, z2, F, pos, denom, cnt, out);
    kgemm<<<64 * CQ_, 320, 0, stream>>>(F, denom, cnt, pos, out);
}

// Round 8
// 111.602 us; speedup vs baseline: 1.2410x; 1.1969x over previous
//
#include <hip/hip_runtime.h>
#include <hip/hip_bf16.h>
#include <stdint.h>

#define NS_ 4096
#define M_  8192
#define D_  256
#define TEMP 0.07f
#define EXP_SCALE 20.61707212818536f   // log2(e)/0.07 : exp(sim/T) = exp2(sim*EXP_SCALE)
#define LN2 0.6931471805599453f
#define CQ_ 16                          // col-blocks per rtile (16 x 512 cols)

typedef short bf16x8 __attribute__((ext_vector_type(8)));
typedef float f32x4  __attribute__((ext_vector_type(4)));
typedef unsigned short ushortx4 __attribute__((ext_vector_type(4)));

static __device__ inline unsigned short f2bf(float x) {
    unsigned u = __float_as_uint(x);
    u += 0x7fffu + ((u >> 16) & 1u);
    return (unsigned short)(u >> 16);
}

static __device__ inline float cleanf(float v) {
    return __builtin_isfinite(v) ? v : 0.0f;
}

// async 16B global -> LDS (lane-contiguous LDS destination required)
#define LDS_LOAD16(gp, lp) \
    __builtin_amdgcn_global_load_lds((const __attribute__((address_space(1))) uint32_t*)(gp), \
                                     (__attribute__((address_space(3))) uint32_t*)(lp), 16, 0, 0)

// ---------------- Kernel 1: clean + normalize -> bf16 F, fp32 pos[]; zero denom/cnt/out -
// grid = 1024, block = 256 (4 waves, one wave per paired row)
__global__ __launch_bounds__(256) void knorm(const float* __restrict__ z1,
                                             const float* __restrict__ z2,
                                             short* __restrict__ F,
                                             float* __restrict__ pos,
                                             float* __restrict__ denom,
                                             int* __restrict__ cnt,
                                             float* __restrict__ out) {
    const int wave = threadIdx.x >> 6;
    const int t    = threadIdx.x & 63;
    const int i    = blockIdx.x * 4 + wave;       // 0..NS-1
    const float4* p1 = (const float4*)(z1 + (size_t)i * D_);
    const float4* p2 = (const float4*)(z2 + (size_t)i * D_);
    float4 a = p1[t], b = p2[t];
    a.x = cleanf(a.x); a.y = cleanf(a.y); a.z = cleanf(a.z); a.w = cleanf(a.w);
    b.x = cleanf(b.x); b.y = cleanf(b.y); b.z = cleanf(b.z); b.w = cleanf(b.w);

    float s1 = a.x*a.x + a.y*a.y + a.z*a.z + a.w*a.w;
    float s2 = b.x*b.x + b.y*b.y + b.z*b.z + b.w*b.w;
    float dp = a.x*b.x + a.y*b.y + a.z*b.z + a.w*b.w;
    #pragma unroll
    for (int m = 1; m < 64; m <<= 1) {
        s1 += __shfl_xor(s1, m);
        s2 += __shfl_xor(s2, m);
        dp += __shfl_xor(dp, m);
    }
    const float inv1 = 1.0f / fmaxf(sqrtf(s1), 1e-12f);
    const float inv2 = 1.0f / fmaxf(sqrtf(s2), 1e-12f);

    ushortx4 o1, o2;
    o1.x = f2bf(a.x * inv1); o1.y = f2bf(a.y * inv1); o1.z = f2bf(a.z * inv1); o1.w = f2bf(a.w * inv1);
    o2.x = f2bf(b.x * inv2); o2.y = f2bf(b.y * inv2); o2.z = f2bf(b.z * inv2); o2.w = f2bf(b.w * inv2);
    ((ushortx4*)(F + (size_t)i * D_))[t]          = o1;
    ((ushortx4*)(F + (size_t)(i + NS_) * D_))[t]  = o2;

    if (t == 0) pos[i] = dp * inv1 * inv2;                 // exact fp32 positive sim
    const int gid = blockIdx.x * 256 + threadIdx.x;
    if (gid < M_)  denom[gid] = 0.0f;
    if (gid < 64)  cnt[gid] = 0;
    if (gid == 0)  out[0] = 0.0f;
}

// ---------------- Kernel 2: wave-private pipelined fused sim-GEMM -----------------------
// grid = 512 = 32 rtiles (256 rows) x 16 col-blocks (512 cols); 256 thr / 4 waves.
// Wave w owns rows R0+w*64..+64 (afrag K=256 resident, 128 VGPR) and privately streams
// 32 B-tiles of 16 cols (8 KB) through its OWN 2x8KB LDS ring via global_load_lds with
// s_waitcnt vmcnt(8) — NO barriers, NO cross-wave sync anywhere in the main body.
__global__ __launch_bounds__(256, 2) void kgemm(const short* __restrict__ F,
                                                float* __restrict__ denom,
                                                int* __restrict__ cnt,
                                                const float* __restrict__ pos,
                                                float* __restrict__ out) {
    __shared__ short Bl[4][8192];   // per-wave 16 KB = two 8 KB tile buffers
    __shared__ int lastflag;
    __shared__ float red[4];

    const int rtile = blockIdx.x >> 4;   // 32 rtiles
    const int cq    = blockIdx.x & 15;   // 16 col-blocks
    const int R0 = rtile * 256;
    const int C0 = cq * 512;

    const int tid  = threadIdx.x;
    const int lane = tid & 63;
    const int wave = tid >> 6;
    const int c16  = lane & 15;
    const int quad = lane >> 4;
    const int swz  = c16 & 7;

    short* myb = &Bl[wave][0];

    // ---- A prologue (wave-private): rows R0 + wave*64 + [0,64) in two 32-row halves ----
    bf16x8 afrag[4][8];
    #pragma unroll
    for (int h = 0; h < 2; ++h) {
        const short* ga = F + (size_t)(R0 + wave * 64 + h * 32) * D_;
        #pragma unroll
        for (int i = 0; i < 16; ++i) {              // 32 rows = 1024 x 16B chunks
            int c   = i * 64 + lane;
            int row = c >> 5;
            int kg  = (c & 31) ^ (row & 7);
            LDS_LOAD16(ga + row * D_ + kg * 8, myb + c * 8);
        }
        asm volatile("s_waitcnt vmcnt(0)" ::: "memory");
        #pragma unroll
        for (int s2 = 0; s2 < 2; ++s2) {
            const int lr = s2 * 16 + c16;           // local row in this half
            #pragma unroll
            for (int ks = 0; ks < 8; ++ks)
                afrag[h * 2 + s2][ks] = *(const bf16x8*)(myb + lr * 256 +
                                         (((ks * 4 + quad) ^ swz) * 8));
        }
        asm volatile("s_waitcnt lgkmcnt(0)" ::: "memory");  // reads done before reuse
    }

    float accexp[4][4];
    #pragma unroll
    for (int s = 0; s < 4; ++s)
        #pragma unroll
        for (int r = 0; r < 4; ++r) accexp[s][r] = 0.0f;

    // ---- main loop: 32 private tiles of 16 cols, 2-deep ring, vmcnt(8) fences ----------
    #define STAGE(t) do {                                                   \
        const short* _gb = F + (size_t)(C0 + (t) * 16) * D_;                \
        short* _dst = myb + ((t) & 1) * 4096;                               \
        _Pragma("unroll")                                                   \
        for (int _i = 0; _i < 8; ++_i) {                                    \
            int _c   = _i * 64 + lane;                                      \
            int _row = _c >> 5;                                             \
            int _kg  = (_c & 31) ^ (_row & 7);                              \
            LDS_LOAD16(_gb + _row * D_ + _kg * 8, _dst + _c * 8);           \
        }                                                                   \
    } while (0)

    STAGE(0);
    STAGE(1);
    for (int t = 0; t < 32; ++t) {
        if (t < 31) asm volatile("s_waitcnt vmcnt(8)" ::: "memory");
        else        asm volatile("s_waitcnt vmcnt(0)" ::: "memory");

        const short* bb = myb + (t & 1) * 4096;
        bf16x8 bfrag[8];
        #pragma unroll
        for (int ks = 0; ks < 8; ++ks)
            bfrag[ks] = *(const bf16x8*)(bb + c16 * 256 +
                                         (((ks * 4 + quad) ^ swz) * 8));
        f32x4 acc[4];
        #pragma unroll
        for (int s = 0; s < 4; ++s) acc[s] = (f32x4){0.f, 0.f, 0.f, 0.f};
        #pragma unroll
        for (int ks = 0; ks < 8; ++ks)
            #pragma unroll
            for (int s = 0; s < 4; ++s)
                acc[s] = __builtin_amdgcn_mfma_f32_16x16x32_bf16(
                    afrag[s][ks], bfrag[ks], acc[s], 0, 0, 0);

        if (t + 2 < 32) STAGE(t + 2);   // overwrite buf (t&1); our reads already issued

        const int colbase = C0 + t * 16;
        #pragma unroll
        for (int s = 0; s < 4; ++s) {
            const int rowbase = R0 + wave * 64 + s * 16;
            if (colbase != rowbase) {            // uniform fast path
                #pragma unroll
                for (int r = 0; r < 4; ++r)
                    accexp[s][r] += __builtin_amdgcn_exp2f(acc[s][r] * EXP_SCALE);
            } else {                             // diagonal 16x16 tile: mask row==col
                #pragma unroll
                for (int r = 0; r < 4; ++r) {
                    float e = __builtin_amdgcn_exp2f(acc[s][r] * EXP_SCALE);
                    if (c16 == quad * 4 + r) e = 0.0f;
                    accexp[s][r] += e;
                }
            }
        }
    }
    #undef STAGE

    // row sums across the 16 lanes holding each row, one atomic per row
    #pragma unroll
    for (int s = 0; s < 4; ++s)
        #pragma unroll
        for (int r = 0; r < 4; ++r) {
            float v = accexp[s][r];
            v += __shfl_xor(v, 1);
            v += __shfl_xor(v, 2);
            v += __shfl_xor(v, 4);
            v += __shfl_xor(v, 8);
            if (c16 == 0)
                atomicAdd(&denom[R0 + wave * 64 + s * 16 + quad * 4 + r], v);
        }

    // last of 16 blocks per rtile: sum(log(denom[R0..R0+256))) / M -> out (+ pos term)
    __syncthreads();
    if (tid == 0) {
        __threadfence();                              // release our denom adds
        lastflag = (atomicAdd(&cnt[rtile], 1) == CQ_ - 1);
    }
    __syncthreads();
    if (lastflag) {
        __threadfence();                              // acquire others' denom adds
        float v = atomicAdd(&denom[R0 + tid], 0.0f);  // coherent read, 256 rows
        float p = __builtin_amdgcn_logf(v) * (LN2 / (float)M_);
        #pragma unroll
        for (int m = 1; m < 64; m <<= 1) p += __shfl_xor(p, m);
        if (lane == 0) red[wave] = p;
        __syncthreads();
        if (tid == 0) atomicAdd(out, red[0] + red[1] + red[2] + red[3]);
        if (rtile == 0) {                             // pos ready (knorm precedes)
            __syncthreads();                          // protect red reuse
            float sp = 0.0f;
            for (int i = tid; i < NS_; i += 256) sp += pos[i];
            #pragma unroll
            for (int m = 1; m < 64; m <<= 1) sp += __shfl_xor(sp, m);
            if (lane == 0) red[wave] = sp;
            __syncthreads();
            if (tid == 0)
                atomicAdd(out, (red[0] + red[1] + red[2] + red[3]) *
                               (-2.0f / (TEMP * (float)M_)));
        }
    }
}

extern "C" void kernel_launch(void* const* d_in, const int* in_sizes, int n_in,
                              void* d_out, int out_size, void* d_ws, size_t ws_size,
                              hipStream_t stream) {
    const float* z1 = (const float*)d_in[0];
    const float* z2 = (const float*)d_in[1];

    short* F     = (short*)d_ws;                                   // 4 MB
    float* denom = (float*)((char*)d_ws + (size_t)M_ * D_ * 2);    // 32 KB
    int*   cnt   = (int*)(denom + M_);                             // 256 B
    float* pos   = (float*)(cnt + 64);                             // 16 KB
    float* out   = (float*)d_out;

    knorm<<<NS_ / 4, 256, 0, stream>>>(z1, z2, F, pos, denom, cnt, out);
    kgemm<<<32 * CQ_, 256, 0, stream>>>(F, denom, cnt, pos, out);
}